// Round 4
// baseline (1428.370 us; speedup 1.0000x reference)
//
#include <hip/hip_runtime.h>

namespace {

constexpr int kB = 64;
constexpr int kL = 4096;
constexpr float kLrW = 1.0f / 64.0f;
constexpr float kLrF = 1.0f / 128.0f;
constexpr float kGradMax = 30.0f;
constexpr float kEps = 1e-9f;
constexpr int kPF = 8;                 // steps per chunk
constexpr int kNC = kL / kPF;          // 512 chunks

#define DPP_ADD_F32(v, ctrl)                                                   \
    v += __int_as_float(__builtin_amdgcn_update_dpp(                           \
        0, __float_as_int(v), (ctrl), 0xF, 0xF, true))

// 32-lane-group sum: lane31 = sum(lanes 0..31), lane63 = sum(lanes 32..63)
__device__ __forceinline__ float red5(float v) {
    DPP_ADD_F32(v, 0x111);  // row_shr:1
    DPP_ADD_F32(v, 0x112);  // row_shr:2
    DPP_ADD_F32(v, 0x114);  // row_shr:4
    DPP_ADD_F32(v, 0x118);  // row_shr:8
    DPP_ADD_F32(v, 0x142);  // row_bcast:15
    return v;
}

__device__ __forceinline__ float rl(float v, int l) {
    return __int_as_float(__builtin_amdgcn_readlane(__float_as_int(v), l));
}

__device__ __forceinline__ float frcp(float x) { return __builtin_amdgcn_rcpf(x); }
__device__ __forceinline__ float frsq(float x) { return __builtin_amdgcn_rsqf(x); }

__global__ __launch_bounds__(64, 1) void adf_kernel(
    const float* __restrict__ u_r, const float* __restrict__ u_i,
    const float* __restrict__ x_r, const float* __restrict__ x_i,
    const float* __restrict__ w0r_g, const float* __restrict__ w0i_g,
    const float* __restrict__ f0r_g, const float* __restrict__ f0i_g,
    float* __restrict__ out)
{
    const int b = blockIdx.x;
    const int lane = threadIdx.x;     // 0..63
    const int half = lane >> 5;       // output mode this lane owns
    const int tap  = lane & 31;
    const bool lo  = (half == 0);

    // w flat: b*128 + i*64 + j*32 + tap ; lane owns w[half][0][tap], w[half][1][tap]
    const int wbase = b * 128 + half * 64 + tap;
    float wAr = w0r_g[wbase],      wAi = w0i_g[wbase];
    float wBr = w0r_g[wbase + 32], wBi = w0i_g[wbase + 32];

    float fr = f0r_g[b * 2 + half];
    float fi = f0i_g[b * 2 + half];
    float invf0 = frsq(fr * fr + fi * fi);
    float psr = fr * invf0, psm = -fi * invf0;   // psi = conj(f)/|f|

    const float2* __restrict__ ur2 = (const float2*)u_r + (size_t)b * kL * 32;
    const float2* __restrict__ ui2 = (const float2*)u_i + (size_t)b * kL * 32;
    const float2* __restrict__ xr2 = (const float2*)x_r + (size_t)b * kL;
    const float2* __restrict__ xi2 = (const float2*)x_i + (size_t)b * kL;
    float2* __restrict__ ob2 = (float2*)out + (size_t)b * kL * 2;

    float2 AuR[kPF], AuI[kPF], AdR[kPF], AdI[kPF];
    float2 BuR[kPF], BuI[kPF], BdR[kPF], BdI[kPF];
    float suA[kPF], suB[kPF];

    auto loadChunk = [&](float2 (&uR)[kPF], float2 (&uI)[kPF],
                         float2 (&dR)[kPF], float2 (&dI)[kPF], int chunk) {
#pragma unroll
        for (int s = 0; s < kPF; ++s) {
            int t = chunk * kPF + s;
            t = t < kL ? t : kL - 1;           // clamp (tail lookahead garbage)
            uR[s] = ur2[(size_t)t * 32 + tap];
            uI[s] = ui2[(size_t)t * 32 + tap];
            dR[s] = xr2[t];
            dI[s] = xi2[t];
        }
    };

    auto calcSu = [&](float2 (&uR)[kPF], float2 (&uI)[kPF], float (&su)[kPF]) {
#pragma unroll
        for (int s = 0; s < kPF; ++s) {
            float e = uR[s].x * uR[s].x;
            e = fmaf(uR[s].y, uR[s].y, e);
            e = fmaf(uI[s].x, uI[s].x, e);
            e = fmaf(uI[s].y, uI[s].y, e);
            e = red5(e);
            su[s] = kLrW * frcp(rl(e, 31) + kEps);
        }
    };

    loadChunk(AuR, AuI, AdR, AdI, 0);
    loadChunk(BuR, BuI, BdR, BdI, 1);

    // ---- prologue: v(0), nv(0) by direct reduce ----
    float vr, vi, nv;
    {
        const float2 u0 = AuR[0], q0 = AuI[0];
        float pr = wAr * u0.x;
        pr = fmaf(-wAi, q0.x, pr); pr = fmaf(wBr, u0.y, pr); pr = fmaf(-wBi, q0.y, pr);
        float pi = wAr * q0.x;
        pi = fmaf(wAi, u0.x, pi); pi = fmaf(wBr, q0.y, pi); pi = fmaf(wBi, u0.y, pi);
        pr = red5(pr); pi = red5(pi);
        const float v0r = rl(pr, 31), v1r = rl(pr, 63);
        const float v0i = rl(pi, 31), v1i = rl(pi, 63);
        vr = lo ? v0r : v1r;
        vi = lo ? v0i : v1i;
        float ven = v0r * v0r;
        ven = fmaf(v0i, v0i, ven); ven = fmaf(v1r, v1r, ven); ven = fmaf(v1i, v1i, ven);
        nv = -frcp(ven + kEps);
    }

    // ---- one scan step; lookahead reduces for step t+1 issued up front ----
    auto step = [&](int t, const float2 ucR, const float2 ucI,
                    const float2 unR, const float2 unI,
                    const float2 dRv, const float2 dIv, const float su_cur) {
        // (1) lookahead partials: v0(t+1) = <w_t, u_{t+1}>, G = <conj(u_t), u_{t+1}>
        float pr = wAr * unR.x;
        pr = fmaf(-wAi, unI.x, pr); pr = fmaf(wBr, unR.y, pr); pr = fmaf(-wBi, unI.y, pr);
        float pi = wAr * unI.x;
        pi = fmaf(wAi, unR.x, pi); pi = fmaf(wBr, unI.y, pi); pi = fmaf(wBi, unR.y, pi);
        float gr = ucR.x * unR.x;
        gr = fmaf(ucI.x, unI.x, gr); gr = fmaf(ucR.y, unR.y, gr); gr = fmaf(ucI.y, unI.y, gr);
        float gi = ucR.x * unI.x;
        gi = fmaf(-ucI.x, unR.x, gi); gi = fmaf(ucR.y, unI.y, gi); gi = fmaf(-ucI.y, unR.y, gi);
        pr = red5(pr); pi = red5(pi); gr = red5(gr); gi = red5(gi);

        // (2) scalar recurrence for step t (per-half SIMT)
        const float dr = lo ? dRv.x : dRv.y;
        const float di = lo ? dIv.x : dIv.y;
        const float kr = vr * fr - vi * fi;
        const float ki = vr * fi + vi * fr;
        if (tap == 0) ob2[(size_t)t * 2 + half] = make_float2(kr, ki);

        const float efr = dr - kr, efi = di - ki;
        float gfr = nv * (efr * vr + efi * vi);
        float gfi = nv * (efi * vr - efr * vi);
        const float mg = gfr * gfr + gfi * gfi;
        const float sc = fminf(1.0f, kGradMax * frsq(mg));
        gfr *= sc; gfi *= sc;

        // e_w uses psi from state (pre-update f)
        const float ewr = dr * psr - di * psm - vr;
        const float ewi = dr * psm + di * psr - vi;
        const float tr = su_cur * ewr, ti = su_cur * ewi;

        // f update, psi for next step
        fr = fmaf(-kLrF, gfr, fr);
        fi = fmaf(-kLrF, gfi, fi);
        const float invf = frsq(fr * fr + fi * fi);
        psr = fr * invf; psm = -fi * invf;

        // (3) w update (per-lane): w += (tr + i ti) * conj(u_t)
        wAr = fmaf(tr, ucR.x, fmaf(ti, ucI.x, wAr));
        wAi = fmaf(ti, ucR.x, fmaf(-tr, ucI.x, wAi));
        wBr = fmaf(tr, ucR.y, fmaf(ti, ucI.y, wBr));
        wBi = fmaf(ti, ucR.y, fmaf(-tr, ucI.y, wBi));

        // (4) broadcast lookahead results, apply Gram fixup -> v(t+1), nv(t+1)
        const float v0r = rl(pr, 31), v1r = rl(pr, 63);
        const float v0i = rl(pi, 31), v1i = rl(pi, 63);
        const float Gr = rl(gr, 31),  Gi = rl(gi, 31);

        const float otr = __shfl_xor(tr, 32, 64);
        const float oti = __shfl_xor(ti, 32, 64);
        const float t0r = lo ? tr : otr, t0i = lo ? ti : oti;
        const float t1r = lo ? otr : tr, t1i = lo ? oti : ti;

        const float v0rf = fmaf(t0r, Gr, fmaf(-t0i, Gi, v0r));
        const float v0if = fmaf(t0r, Gi, fmaf( t0i, Gr, v0i));
        const float v1rf = fmaf(t1r, Gr, fmaf(-t1i, Gi, v1r));
        const float v1if = fmaf(t1r, Gi, fmaf( t1i, Gr, v1i));

        float ven = v0rf * v0rf;
        ven = fmaf(v0if, v0if, ven); ven = fmaf(v1rf, v1rf, ven); ven = fmaf(v1if, v1if, ven);
        nv = -frcp(ven + kEps);                 // rcp latency hides under next step
        vr = lo ? v0rf : v1rf;
        vi = lo ? v0if : v1if;
    };

    for (int c = 0; c < kNC; c += 2) {
        // chunk c lives in A (arrived), chunk c+1 in B
        calcSu(AuR, AuI, suA);
#pragma unroll
        for (int s = 0; s < kPF - 1; ++s)
            step(c * kPF + s, AuR[s], AuI[s], AuR[s + 1], AuI[s + 1], AdR[s], AdI[s], suA[s]);
        step(c * kPF + kPF - 1, AuR[kPF - 1], AuI[kPF - 1], BuR[0], BuI[0],
             AdR[kPF - 1], AdI[kPF - 1], suA[kPF - 1]);
        loadChunk(AuR, AuI, AdR, AdI, (c + 2 < kNC) ? c + 2 : kNC - 1);  // ~16 steps in flight

        calcSu(BuR, BuI, suB);
#pragma unroll
        for (int s = 0; s < kPF - 1; ++s)
            step((c + 1) * kPF + s, BuR[s], BuI[s], BuR[s + 1], BuI[s + 1], BdR[s], BdI[s], suB[s]);
        step((c + 1) * kPF + kPF - 1, BuR[kPF - 1], BuI[kPF - 1], AuR[0], AuI[0],
             BdR[kPF - 1], BdI[kPF - 1], suB[kPF - 1]);
        loadChunk(BuR, BuI, BdR, BdI, (c + 3 < kNC) ? c + 3 : kNC - 1);
    }
}

} // namespace

extern "C" void kernel_launch(void* const* d_in, const int* in_sizes, int n_in,
                              void* d_out, int out_size, void* d_ws, size_t ws_size,
                              hipStream_t stream) {
    const float* u_r  = (const float*)d_in[0];
    const float* u_i  = (const float*)d_in[1];
    const float* x_r  = (const float*)d_in[2];
    const float* x_i  = (const float*)d_in[3];
    const float* w0_r = (const float*)d_in[4];
    const float* w0_i = (const float*)d_in[5];
    const float* f0_r = (const float*)d_in[6];
    const float* f0_i = (const float*)d_in[7];
    float* out = (float*)d_out;

    dim3 grid(kB);
    dim3 block(64);
    adf_kernel<<<grid, block, 0, stream>>>(u_r, u_i, x_r, x_i,
                                           w0_r, w0_i, f0_r, f0_i, out);
}